// Round 4
// baseline (256.552 us; speedup 1.0000x reference)
//
#include <hip/hip_runtime.h>
#include <cstddef>

#define B_ 8
#define H_ 1024
#define W_ 1024
#define NW_ 5
#define CH_ 32          // column chunks
#define CHR_ (H_ / CH_) // 32 rows per chunk

// ===========================================================================
// Round-4 structure. Measurement insight (R1-R3 fit): dur_us carries a ~145 us
// harness floor (671 MB d_ws re-poison fill @ ~107 us + d_out fill + d_in
// restore). Our kernels were ~107 us (scans 47, k_out 60). This round removes
// the 2-D SAT: only a COLUMN prefix C of centered (x-0.5, x^2-1/3) is
// materialized; the horizontal prefix happens inside k_out in LDS.
// Intermediate traffic 258 MB -> 130 MB.
// ===========================================================================

// ---------------------------------------------------------------------------
// K1: per-(b, chunk, column) sums of centered x and x^2 (for chunk offsets).
// ---------------------------------------------------------------------------
__global__ __launch_bounds__(256) void k_colpart(const float* __restrict__ x,
                                                 float* __restrict__ part1,
                                                 float* __restrict__ part2) {
  const int xx = blockIdx.x * 256 + threadIdx.x;
  const int ch = blockIdx.y, b = blockIdx.z;
  const float* p = x + ((size_t)b * H_ + (size_t)ch * CHR_) * W_ + xx;
  float s1 = 0.f, s2 = 0.f;
  #pragma unroll 8
  for (int i = 0; i < CHR_; ++i) {
    const float v = p[(size_t)i * W_];
    s1 += v - 0.5f;
    s2 += v * v - (1.0f / 3.0f);
  }
  const size_t o = ((size_t)(b * CH_ + ch)) * W_ + xx;
  part1[o] = s1; part2[o] = s2;
}

// ---------------------------------------------------------------------------
// K2: column scan. Each block sums its <32 L2-resident part rows for the
// exclusive chunk offset (absorbs the chunkscan kernel), then re-reads its
// 32 x-rows, centers, scans, writes C1/C2 (column-inclusive prefixes).
// ---------------------------------------------------------------------------
__global__ __launch_bounds__(256) void k_colscan(const float* __restrict__ x,
                                                 float* __restrict__ C1,
                                                 float* __restrict__ C2,
                                                 const float* __restrict__ part1,
                                                 const float* __restrict__ part2) {
  const int xx = blockIdx.x * 256 + threadIdx.x;
  const int ch = blockIdx.y, b = blockIdx.z;
  float r1 = 0.f, r2 = 0.f;
  for (int c = 0; c < ch; ++c) {   // block-uniform trip count
    const size_t o = ((size_t)(b * CH_ + c)) * W_ + xx;
    r1 += part1[o];
    r2 += part2[o];
  }
  const size_t base = ((size_t)b * H_ + (size_t)ch * CHR_) * W_ + xx;
  #pragma unroll 8
  for (int i = 0; i < CHR_; ++i) {
    const size_t o = base + (size_t)i * W_;
    const float v = x[o];
    r1 += v - 0.5f;
    r2 += v * v - (1.0f / 3.0f);
    C1[o] = r1;
    C2[o] = r2;
  }
}

// ---------------------------------------------------------------------------
// K3: per output row y:
//   phase 1: D_w[x] = C[yB_w][x] - C[yT_w][x]  (20 coalesced float4 row loads)
//   phase 1.5: per-wave shuffle-scan of each 1024-wide D plane in LDS -> H
//   phase 2: box = H[xR] - H[xL]; Sauvola with analytic counts.
// XCD swizzle: blockIdx%8 owns a contiguous 128-row y-slab per batch (slab
// working set ~2 MB fits per-XCD L2). Phase-2 LDS reads are lane-stride-1
// (2-way bank aliasing = free, m136).
// ---------------------------------------------------------------------------
__global__ __launch_bounds__(256) void k_out(const float* __restrict__ C1,
                                             const float* __restrict__ C2,
                                             const float* __restrict__ kk,
                                             const float* __restrict__ RR,
                                             float* __restrict__ out) {
  const int i = blockIdx.x;
  const int xcd = i & 7;
  const int s = i >> 3;
  const int b = s >> 7;
  const int y = xcd * 128 + (s & 127);
  const int t = threadIdx.x;

  __shared__ float lds[2 * NW_ * W_];  // 40 KB: plane (2w+m)

  const float* base1 = C1 + (size_t)b * H_ * W_;
  const float* base2 = C2 + (size_t)b * H_ * W_;
  const int rad[NW_] = {3, 7, 15, 31, 63};

  // phase 1: vertical box sums (column direction done by prefix difference)
  #pragma unroll
  for (int w = 0; w < NW_; ++w) {
    const int r = rad[w];
    const int yB = min(y + r, H_ - 1);
    const int yT = y - r - 1;
    const float4 fb1 = reinterpret_cast<const float4*>(base1 + (size_t)yB * W_)[t];
    const float4 fb2 = reinterpret_cast<const float4*>(base2 + (size_t)yB * W_)[t];
    float4 ft1 = {0.f, 0.f, 0.f, 0.f}, ft2 = {0.f, 0.f, 0.f, 0.f};
    if (yT >= 0) {   // block-uniform branch
      ft1 = reinterpret_cast<const float4*>(base1 + (size_t)yT * W_)[t];
      ft2 = reinterpret_cast<const float4*>(base2 + (size_t)yT * W_)[t];
    }
    float4 d1, d2;
    d1.x = fb1.x - ft1.x; d1.y = fb1.y - ft1.y; d1.z = fb1.z - ft1.z; d1.w = fb1.w - ft1.w;
    d2.x = fb2.x - ft2.x; d2.y = fb2.y - ft2.y; d2.z = fb2.z - ft2.z; d2.w = fb2.w - ft2.w;
    reinterpret_cast<float4*>(lds + (size_t)(2 * w) * W_)[t] = d1;
    reinterpret_cast<float4*>(lds + (size_t)(2 * w + 1) * W_)[t] = d2;
  }
  __syncthreads();

  // phase 1.5: horizontal inclusive scan of each plane (wave-parallel,
  // 4 groups of 256 per plane, 6-round __shfl_up, carried between groups)
  const int wave = t >> 6, lane = t & 63;
  for (int p = wave; p < 2 * NW_; p += 4) {
    float* D = lds + (size_t)p * W_;
    float carry = 0.f;
    #pragma unroll
    for (int g = 0; g < 4; ++g) {
      const float4 v = reinterpret_cast<const float4*>(D + g * 256)[lane];
      const float l0 = v.x;
      const float l1 = l0 + v.y;
      const float l2 = l1 + v.z;
      const float l3 = l2 + v.w;
      float inc = l3;
      #pragma unroll
      for (int off = 1; off < 64; off <<= 1) {
        const float u = __shfl_up(inc, off);
        if (lane >= off) inc += u;
      }
      const float bse = carry + inc - l3;
      float4 o;
      o.x = bse + l0; o.y = bse + l1; o.z = bse + l2; o.w = bse + l3;
      reinterpret_cast<float4*>(D + g * 256)[lane] = o;
      carry += __shfl(inc, 63);
    }
  }
  __syncthreads();

  // phase 2: corner differences + Sauvola
  #pragma unroll
  for (int w = 0; w < NW_; ++w) {
    const int r = rad[w];
    const float kw = kk[w];
    const float invR = __builtin_amdgcn_rcpf(RR[w]);
    const int yB = min(y + r, H_ - 1);
    const float rows = (float)(yB - max(y - r, 0) + 1);
    const float* H1 = lds + (size_t)(2 * w) * W_;
    const float* H2 = lds + (size_t)(2 * w + 1) * W_;
    float* orow = out + (((size_t)(b * NW_ + w)) * H_ + y) * W_;
    #pragma unroll
    for (int kp = 0; kp < 4; ++kp) {
      const int xx = t + kp * 256;
      const int xR = min(xx + r, W_ - 1);
      const int xL = xx - r - 1;
      float s1 = H1[xR];
      float s2 = H2[xR];
      if (xL >= 0) { s1 -= H1[xL]; s2 -= H2[xL]; }
      const float cols = (float)(xR - max(xx - r, 0) + 1);
      const float inv = __builtin_amdgcn_rcpf(rows * cols);
      const float Ex  = s1 * inv + 0.5f;
      const float Ex2 = s2 * inv + (1.0f / 3.0f);
      const float var = Ex2 - Ex * Ex;
      const float dev = __builtin_amdgcn_sqrtf(fmaxf(var, 1e-6f));
      orow[xx] = Ex * (1.0f + kw * (dev * invR - 1.0f));
    }
  }
}

// ---------------------------------------------------------------------------
extern "C" void kernel_launch(void* const* d_in, const int* in_sizes, int n_in,
                              void* d_out, int out_size, void* d_ws, size_t ws_size,
                              hipStream_t stream) {
  const float* x  = (const float*)d_in[0];
  const float* kk = (const float*)d_in[1];
  const float* RR = (const float*)d_in[2];
  float* out = (float*)d_out;

  const size_t plane = (size_t)B_ * H_ * W_;            // 32 MB per moment
  float* C1 = (float*)d_ws;
  float* C2 = C1 + plane;
  float* part1 = C2 + plane;                            // 1 MB each
  float* part2 = part1 + (size_t)B_ * CH_ * W_;

  k_colpart <<<dim3(W_/256, CH_, B_), 256, 0, stream>>>(x, part1, part2);
  k_colscan <<<dim3(W_/256, CH_, B_), 256, 0, stream>>>(x, C1, C2, part1, part2);
  k_out     <<<dim3(B_ * H_),         256, 0, stream>>>(C1, C2, kk, RR, out);
}